// Round 11
// baseline (2646.833 us; speedup 1.0000x reference)
//
#include <hip/hip_runtime.h>
#include <cstdint>
#include <cstddef>

// RNNLayer: B=64, T=1024, IN=512, H=512, fp32 in/out.
// Phase 1: Wx = X @ W_w^T + (W_b + U_b)  (f16 MFMA GEMM) -> d_out.
// Phase 2: VALU scan, one WG (512 threads, 8 waves) per batch, 64 CUs.
//   Thread j owns output row j: 256 f16-MAC-pairs per step.
//   Round-11 change vs round 9 (passing, 2.34ms): the MAC core uses
//   v_pk_fma_f16 (__builtin_elementwise_fma on f16x2 -- compiler-generated,
//   NO inline asm; rounds 8/10 proved hand-emitted dot2 is numerically
//   unsafe). Cycle accounting of round 9 (4400 cy/SIMD/step vs 3180
//   expected at 2cy/instr) fits v_dot2_f32_f16 being half-rate; pk_fma_f16
//   is the marketed full-rate fp16 path. 8 persistent f16x2 accumulators
//   (32 terms each, ~8e-4/step extra rounding) folded to f32 once per step.
//   U[j, 0:416) = 208 f16x2 in regs; U[j, 416:512) = 48 pairs in LDS,
//   column-major Ut32[pair][tid] (b32, 2 lanes/bank, conflict-free).
//   h broadcast: one b128 LDS read/lane gathers all 512 h, readlane -> pk_fma.
//   One barrier/step (raw lgkmcnt+s_barrier), h double-buffered in LDS.

#define T_STEPS 1024
#define NPV 208                 // u pairs in VGPRs (k < 416)
#define NTP 48                  // tail pairs in LDS  (k in [416,512))

using f16 = _Float16;
typedef f16  f16x2 __attribute__((ext_vector_type(2)));
typedef f16  f16x8 __attribute__((ext_vector_type(8)));
typedef float f32x4 __attribute__((ext_vector_type(4)));

static __device__ __forceinline__ f16x8 cvt8(float4 v0, float4 v1) {
    return (f16x8){ (f16)v0.x, (f16)v0.y, (f16)v0.z, (f16)v0.w,
                    (f16)v1.x, (f16)v1.y, (f16)v1.z, (f16)v1.w };
}
static __device__ __forceinline__ f16x2 pack2f(float2 v) {
    return (f16x2){ (f16)v.x, (f16)v.y };
}
static __device__ __forceinline__ int pack2i(float2 v) {
    return __builtin_bit_cast(int, pack2f(v));
}
static __device__ __forceinline__ f16x2 asf16x2(int v) {
    return __builtin_bit_cast(f16x2, v);
}

// ---------------------------------------------------------------------------
// Kernel 1: Wx GEMM (bias includes U_b). Unchanged (proven).
// ---------------------------------------------------------------------------
__global__ __launch_bounds__(256, 2)
void gemm_wx(const float* __restrict__ X, const float* __restrict__ W,
             const float* __restrict__ Wb, const float* __restrict__ Ub,
             float* __restrict__ out) {
    __shared__ __align__(16) char Al[128 * 128];
    __shared__ __align__(16) char Bl[128 * 128];

    const int tid  = threadIdx.x;
    const int lane = tid & 63;
    const int wid  = tid >> 6;
    const int wm   = wid & 1;
    const int wn   = wid >> 1;
    const int m0   = blockIdx.x * 128;
    const int n0   = blockIdx.y * 128;

    f32x4 acc[4][4] = {};

    for (int kt = 0; kt < 512; kt += 64) {
        __syncthreads();
#pragma unroll
        for (int i = 0; i < 4; ++i) {
            const int id   = tid + i * 256;
            const int row  = id >> 3;
            const int slot = id & 7;
            const float4* pa = reinterpret_cast<const float4*>(
                X + (size_t)(m0 + row) * 512 + kt + slot * 8);
            const float4* pb = reinterpret_cast<const float4*>(
                W + (size_t)(n0 + row) * 512 + kt + slot * 8);
            f16x8 va = cvt8(pa[0], pa[1]);
            f16x8 vb = cvt8(pb[0], pb[1]);
            const int cb = (slot * 16) ^ ((row & 7) << 4);
            *reinterpret_cast<f16x8*>(Al + row * 128 + cb) = va;
            *reinterpret_cast<f16x8*>(Bl + row * 128 + cb) = vb;
        }
        __syncthreads();

#pragma unroll
        for (int kk = 0; kk < 2; ++kk) {
            f16x8 af[4], bf[4];
#pragma unroll
            for (int mi = 0; mi < 4; ++mi) {
                const int r  = wm * 64 + mi * 16 + (lane & 15);
                const int cb = (kk * 64 + ((lane >> 4) * 16)) ^ ((r & 7) << 4);
                af[mi] = *reinterpret_cast<const f16x8*>(Al + r * 128 + cb);
            }
#pragma unroll
            for (int ni = 0; ni < 4; ++ni) {
                const int r  = wn * 64 + ni * 16 + (lane & 15);
                const int cb = (kk * 64 + ((lane >> 4) * 16)) ^ ((r & 7) << 4);
                bf[ni] = *reinterpret_cast<const f16x8*>(Bl + r * 128 + cb);
            }
#pragma unroll
            for (int mi = 0; mi < 4; ++mi)
#pragma unroll
                for (int ni = 0; ni < 4; ++ni)
                    acc[mi][ni] = __builtin_amdgcn_mfma_f32_16x16x32_f16(
                        af[mi], bf[ni], acc[mi][ni], 0, 0, 0);
        }
    }

#pragma unroll
    for (int ni = 0; ni < 4; ++ni) {
        const int col  = n0 + wn * 64 + ni * 16 + (lane & 15);
        const float bias = Wb[col] + Ub[col];
#pragma unroll
        for (int mi = 0; mi < 4; ++mi) {
            const int rowb = m0 + wm * 64 + mi * 16 + ((lane >> 4) * 4);
#pragma unroll
            for (int e = 0; e < 4; ++e)
                out[(size_t)(rowb + e) * 512 + col] = acc[mi][ni][e] + bias;
        }
    }
}

// ---------------------------------------------------------------------------
// Kernel 2: VALU scan (pk_fma_f16 core).
// ---------------------------------------------------------------------------
__global__ __launch_bounds__(512, 2)
void rnn_scan(float* __restrict__ out, const float* __restrict__ h0,
              const float* __restrict__ Uw) {
    __shared__ __align__(16) int  Ut32[NTP * 512];  // tail pairs, col-major, 96KB
    __shared__ __align__(16) char hb[2][1024];      // h as f16[512], dbuf

    const int tid  = threadIdx.x;    // = output row j
    const int b    = blockIdx.x;
    const int lane = tid & 63;

    // ---- U[j, 0:416) -> 208 packed f16x2 registers.
    const float2* up = reinterpret_cast<const float2*>(Uw + (size_t)tid * 512);
    f16x2 uv[NPV];
#pragma unroll
    for (int p = 0; p < NPV; ++p)
        uv[p] = pack2f(up[p]);

    // ---- U[j, 416:512) -> LDS column-major: Ut32[pair c][tid].
    {
        const float2* tp = reinterpret_cast<const float2*>(
            Uw + (size_t)tid * 512 + 416);
#pragma unroll
        for (int c = 0; c < NTP; ++c)
            Ut32[c * 512 + tid] = pack2i(tp[c]);
    }

    // ---- h_0 -> hb[0] (f16 linear; lane l later gathers pairs 4l..4l+3).
    *reinterpret_cast<f16*>(hb[0] + 2 * tid) = (f16)h0[b * 512 + tid];

    float* const obase = out + (size_t)b * (T_STEPS * 512);
    float wx = obase[tid];           // Wx row 0 (gemm_wx done; same stream)
    __syncthreads();

    for (int t = 0; t < T_STEPS; ++t) {
        // Full h_{t-1} gathered into the wave: lane l holds pairs 4l..4l+3.
        const uint4 vh = *reinterpret_cast<const uint4*>(hb[t & 1] + 16 * lane);
        // Prefetch next step's Wx (~1 step of latency cover).
        float wxn = 0.0f;
        if (t < T_STEPS - 1) wxn = obase[(size_t)(t + 1) * 512 + tid];

        // 8 persistent f16x2 accumulators; pair p feeds c[p & 7] (32 terms
        // per accumulator lane -> bounded f16 accumulation error).
        f16x2 c[8] = {};

        // Register part: pairs 0..207 (k < 416). Pair q: lane q>>2, comp q&3.
#pragma unroll
        for (int q4 = 0; q4 < NPV / 4; ++q4) {
            const int h0_ = __builtin_amdgcn_readlane((int)vh.x, q4);
            const int h1_ = __builtin_amdgcn_readlane((int)vh.y, q4);
            const int h2_ = __builtin_amdgcn_readlane((int)vh.z, q4);
            const int h3_ = __builtin_amdgcn_readlane((int)vh.w, q4);
            const int a0 = (4 * q4 + 0) & 7, a1 = (4 * q4 + 1) & 7;
            const int a2 = (4 * q4 + 2) & 7, a3 = (4 * q4 + 3) & 7;
            c[a0] = __builtin_elementwise_fma(uv[4 * q4 + 0], asf16x2(h0_), c[a0]);
            c[a1] = __builtin_elementwise_fma(uv[4 * q4 + 1], asf16x2(h1_), c[a1]);
            c[a2] = __builtin_elementwise_fma(uv[4 * q4 + 2], asf16x2(h2_), c[a2]);
            c[a3] = __builtin_elementwise_fma(uv[4 * q4 + 3], asf16x2(h3_), c[a3]);
        }
        // Tail: pairs 208..255 (k in [416,512)), U pairs via conflict-free b32.
#pragma unroll
        for (int cc = 0; cc < NTP; cc += 4) {
            const int ln  = NPV / 4 + (cc >> 2);
            const int h0_ = __builtin_amdgcn_readlane((int)vh.x, ln);
            const int h1_ = __builtin_amdgcn_readlane((int)vh.y, ln);
            const int h2_ = __builtin_amdgcn_readlane((int)vh.z, ln);
            const int h3_ = __builtin_amdgcn_readlane((int)vh.w, ln);
            const int a0 = (cc + 0) & 7, a1 = (cc + 1) & 7;
            const int a2 = (cc + 2) & 7, a3 = (cc + 3) & 7;
            c[a0] = __builtin_elementwise_fma(asf16x2(Ut32[(cc + 0) * 512 + tid]),
                                              asf16x2(h0_), c[a0]);
            c[a1] = __builtin_elementwise_fma(asf16x2(Ut32[(cc + 1) * 512 + tid]),
                                              asf16x2(h1_), c[a1]);
            c[a2] = __builtin_elementwise_fma(asf16x2(Ut32[(cc + 2) * 512 + tid]),
                                              asf16x2(h2_), c[a2]);
            c[a3] = __builtin_elementwise_fma(asf16x2(Ut32[(cc + 3) * 512 + tid]),
                                              asf16x2(h3_), c[a3]);
        }

        // Fold the 16 f16 partials to f32 (once per step).
        float f0 = 0.f, f1 = 0.f, f2 = 0.f, f3 = 0.f;
#pragma unroll
        for (int i = 0; i < 8; i += 4) {
            f0 += (float)c[i + 0][0] + (float)c[i + 0][1];
            f1 += (float)c[i + 1][0] + (float)c[i + 1][1];
            f2 += (float)c[i + 2][0] + (float)c[i + 2][1];
            f3 += (float)c[i + 3][0] + (float)c[i + 3][1];
        }

        // tanh (round-2/3 proven form).
        const float aa = ((f0 + f1) + (f2 + f3)) + wx;   // U_b folded into Wx
        const float ax = fabsf(aa);
        const float e  = __expf(2.0f * ax);
        const float r1 = 1.0f - 2.0f / (e + 1.0f);       // tanh(|aa|); e=inf -> 1
        const float h  = copysignf(r1, aa);

        // LDS write first (so the pre-barrier lgkm drain is old), then global.
        *reinterpret_cast<f16*>(hb[(t + 1) & 1] + 2 * tid) = (f16)h;
        obase[(size_t)t * 512 + tid] = h;          // overwrite consumed Wx
        wx = wxn;

        // One barrier: h(t) LDS write drained (lgkmcnt only; global stores
        // stay in flight), then all waves step together.
        asm volatile("s_waitcnt lgkmcnt(0)\n\ts_barrier" ::: "memory");
    }
}

// ---------------------------------------------------------------------------
extern "C" void kernel_launch(void* const* d_in, const int* in_sizes, int n_in,
                              void* d_out, int out_size, void* d_ws, size_t ws_size,
                              hipStream_t stream) {
    const float* X  = (const float*)d_in[0];
    const float* h0 = (const float*)d_in[1];
    const float* Ww = (const float*)d_in[2];
    const float* Wb = (const float*)d_in[3];
    const float* Uw = (const float*)d_in[4];
    const float* Ub = (const float*)d_in[5];
    float* out = (float*)d_out;

    gemm_wx<<<dim3(512, 4), dim3(256), 0, stream>>>(X, Ww, Wb, Ub, out);
    rnn_scan<<<dim3(64), dim3(512), 0, stream>>>(out, h0, Uw);
}